// Round 1
// baseline (59.627 us; speedup 1.0000x reference)
//
#include <hip/hip_runtime.h>

// OctMLP: x (B,S,4,E) complex pairs, weights reduced to row-sum vectors,
// elementwise octonion-ish multiply with soft-shrink, bias, shrink, stack.
// Memory-bound: ~264 MiB total traffic -> target ~45 us.

constexpr int Bc = 8, Sc = 1024, Ec = 512;
constexpr int Nc = Bc * Sc * Ec;          // 4194304 elements per plane
constexpr float LAM = 0.01f;

__device__ __forceinline__ float sshrink(float v) {
    // branchless: copysign(max(|v|-L,0), v)
    float a = fabsf(v) - LAM;
    a = fmaxf(a, 0.0f);
    return copysignf(a, v);
}

// One wave (64 lanes) per row; 8 matrices x 512 rows = 4096 waves.
__global__ __launch_bounds__(256) void rowsum_kernel(
    const float* __restrict__ y1r, const float* __restrict__ y1i,
    const float* __restrict__ y2r, const float* __restrict__ y2i,
    const float* __restrict__ y3r, const float* __restrict__ y3i,
    const float* __restrict__ y4r, const float* __restrict__ y4i,
    float* __restrict__ sums)
{
    int gid  = blockIdx.x * blockDim.x + threadIdx.x;
    int wave = gid >> 6;
    int lane = gid & 63;
    if (wave >= 8 * Ec) return;
    int m   = wave >> 9;   // matrix 0..7
    int row = wave & 511;

    const float* src;
    switch (m) {
        case 0: src = y1r; break;
        case 1: src = y1i; break;
        case 2: src = y2r; break;
        case 3: src = y2i; break;
        case 4: src = y3r; break;
        case 5: src = y3i; break;
        case 6: src = y4r; break;
        default: src = y4i; break;
    }
    src += (size_t)row * Ec;

    float s = 0.0f;
    #pragma unroll
    for (int j = 0; j < 8; ++j) s += src[lane + j * 64];
    #pragma unroll
    for (int off = 32; off >= 1; off >>= 1) s += __shfl_down(s, off, 64);
    if (lane == 0) sums[m * Ec + row] = s;
}

#define F4LD(p) (*reinterpret_cast<const float4*>(p))
#define F4ST(p, v) (*reinterpret_cast<float4*>(p) = (v))
#define ELT(v, j) (reinterpret_cast<const float*>(&(v))[j])

// One thread per 4 consecutive e. N/4 = 1048576 threads.
__global__ __launch_bounds__(256) void octmlp_kernel(
    const float* __restrict__ xr, const float* __restrict__ xi,
    const float* __restrict__ sums,
    const float* __restrict__ bR1, const float* __restrict__ bI1,
    const float* __restrict__ bR2, const float* __restrict__ bI2,
    const float* __restrict__ bR3, const float* __restrict__ bI3,
    const float* __restrict__ bR4, const float* __restrict__ bI4,
    float* __restrict__ out)
{
    constexpr int E4 = Ec / 4;                    // 128 float4 per row
    int idx = blockIdx.x * blockDim.x + threadIdx.x;   // 0 .. N/4-1
    int e4  = idx & (E4 - 1);
    int bs  = idx >> 7;                           // b*S+s
    int e   = e4 * 4;

    const size_t xbase = (size_t)bs * 4 * Ec + e;
    // x[k] components, k = octonion slot 0..3
    float4 x1r = F4LD(xr + xbase + 0 * Ec), x1i = F4LD(xi + xbase + 0 * Ec);
    float4 x2r = F4LD(xr + xbase + 1 * Ec), x2i = F4LD(xi + xbase + 1 * Ec);
    float4 x3r = F4LD(xr + xbase + 2 * Ec), x3i = F4LD(xi + xbase + 2 * Ec);
    float4 x4r = F4LD(xr + xbase + 3 * Ec), x4i = F4LD(xi + xbase + 3 * Ec);

    // sum vectors: layout [m][E], m order = r1,i1,r2,i2,r3,i3,r4,i4
    float4 R1 = F4LD(sums + 0 * Ec + e), I1 = F4LD(sums + 1 * Ec + e);
    float4 R2 = F4LD(sums + 2 * Ec + e), I2 = F4LD(sums + 3 * Ec + e);
    float4 R3 = F4LD(sums + 4 * Ec + e), I3 = F4LD(sums + 5 * Ec + e);
    float4 R4 = F4LD(sums + 6 * Ec + e), I4 = F4LD(sums + 7 * Ec + e);

    float4 vbR1 = F4LD(bR1 + e), vbI1 = F4LD(bI1 + e);
    float4 vbR2 = F4LD(bR2 + e), vbI2 = F4LD(bI2 + e);
    float4 vbR3 = F4LD(bR3 + e), vbI3 = F4LD(bI3 + e);
    float4 vbR4 = F4LD(bR4 + e), vbI4 = F4LD(bI4 + e);

    float4 o1r, o1i, o2r, o2i, o3r, o3i, o4r, o4i;

    #pragma unroll
    for (int j = 0; j < 4; ++j) {
        float a1r = ELT(x1r, j), a1i = ELT(x1i, j);
        float a2r = ELT(x2r, j), a2i = ELT(x2i, j);
        float a3r = ELT(x3r, j), a3i = ELT(x3i, j);
        float a4r = ELT(x4r, j), a4i = ELT(x4i, j);
        float r1 = ELT(R1, j), i1 = ELT(I1, j);
        float r2 = ELT(R2, j), i2 = ELT(I2, j);
        float r3 = ELT(R3, j), i3 = ELT(I3, j);
        float r4 = ELT(R4, j), i4 = ELT(I4, j);

        // cmul normal (s = r + i*I):  re = sh(xr*r - xi*i), im = sh(xr*i + xi*r)
        // cmul conj   (s = r - i*I):  re = sh(xr*r + xi*i), im = sh(xi*r - xr*i)
        #define CMUL(or_, oi_, xr_, xi_, r_, i_) \
            float or_ = sshrink((xr_) * (r_) - (xi_) * (i_)); \
            float oi_ = sshrink((xr_) * (i_) + (xi_) * (r_));
        #define CMULC(or_, oi_, xr_, xi_, r_, i_) \
            float or_ = sshrink((xr_) * (r_) + (xi_) * (i_)); \
            float oi_ = sshrink((xi_) * (r_) - (xr_) * (i_));

        // a1 = cmul(x1,c1) - cmulc(x2,c2) - cmulc(x3,c3) - cmulc(x4,c4)
        CMUL (p11r, p11i, a1r, a1i, r1, i1)
        CMULC(p12r, p12i, a2r, a2i, r2, i2)
        CMULC(p13r, p13i, a3r, a3i, r3, i3)
        CMULC(p14r, p14i, a4r, a4i, r4, i4)
        float A1r = p11r - p12r - p13r - p14r;
        float A1i = p11i - p12i - p13i - p14i;

        // a2 = cmul(x2,c1) + cmul(x1,c2) + cmulc(x4,c3) - cmulc(x3,c4)
        CMUL (p21r, p21i, a2r, a2i, r1, i1)
        CMUL (p22r, p22i, a1r, a1i, r2, i2)
        CMULC(p23r, p23i, a4r, a4i, r3, i3)
        CMULC(p24r, p24i, a3r, a3i, r4, i4)
        float A2r = p21r + p22r + p23r - p24r;
        float A2i = p21i + p22i + p23i - p24i;

        // a3 = cmul(x3,c1) - cmulc(x4,c2) + cmul(x1,c3) + cmulc(x2,c4)
        CMUL (p31r, p31i, a3r, a3i, r1, i1)
        CMULC(p32r, p32i, a4r, a4i, r2, i2)
        CMUL (p33r, p33i, a1r, a1i, r3, i3)
        CMULC(p34r, p34i, a2r, a2i, r4, i4)
        float A3r = p31r - p32r + p33r + p34r;
        float A3i = p31i - p32i + p33i + p34i;

        // a4 = cmul(x4,c1) + cmulc(x3,c2) - cmulc(x2,c3) + cmul(x1,c4)
        CMUL (p41r, p41i, a4r, a4i, r1, i1)
        CMULC(p42r, p42i, a3r, a3i, r2, i2)
        CMULC(p43r, p43i, a2r, a2i, r3, i3)
        CMUL (p44r, p44i, a1r, a1i, r4, i4)
        float A4r = p41r + p42r - p43r + p44r;
        float A4i = p41i + p42i - p43i + p44i;

        reinterpret_cast<float*>(&o1r)[j] = sshrink(A1r + ELT(vbR1, j));
        reinterpret_cast<float*>(&o1i)[j] = sshrink(A1i + ELT(vbI1, j));
        reinterpret_cast<float*>(&o2r)[j] = sshrink(A2r + ELT(vbR2, j));
        reinterpret_cast<float*>(&o2i)[j] = sshrink(A2i + ELT(vbI2, j));
        reinterpret_cast<float*>(&o3r)[j] = sshrink(A3r + ELT(vbR3, j));
        reinterpret_cast<float*>(&o3i)[j] = sshrink(A3i + ELT(vbI3, j));
        reinterpret_cast<float*>(&o4r)[j] = sshrink(A4r + ELT(vbR4, j));
        reinterpret_cast<float*>(&o4i)[j] = sshrink(A4i + ELT(vbI4, j));
        #undef CMUL
        #undef CMULC
    }

    // out[c][p][b][s][e]: plane stride N, bs row stride E
    float* obase = out + (size_t)bs * Ec + e;
    F4ST(obase + 0ull * Nc, o1r);
    F4ST(obase + 1ull * Nc, o1i);
    F4ST(obase + 2ull * Nc, o2r);
    F4ST(obase + 3ull * Nc, o2i);
    F4ST(obase + 4ull * Nc, o3r);
    F4ST(obase + 5ull * Nc, o3i);
    F4ST(obase + 6ull * Nc, o4r);
    F4ST(obase + 7ull * Nc, o4i);
}

extern "C" void kernel_launch(void* const* d_in, const int* in_sizes, int n_in,
                              void* d_out, int out_size, void* d_ws, size_t ws_size,
                              hipStream_t stream) {
    const float* xr  = (const float*)d_in[0];
    const float* xi  = (const float*)d_in[1];
    const float* y1r = (const float*)d_in[2];
    const float* y1i = (const float*)d_in[3];
    const float* y2r = (const float*)d_in[4];
    const float* y2i = (const float*)d_in[5];
    const float* y3r = (const float*)d_in[6];
    const float* y3i = (const float*)d_in[7];
    const float* y4r = (const float*)d_in[8];
    const float* y4i = (const float*)d_in[9];
    const float* bR1 = (const float*)d_in[10];
    const float* bI1 = (const float*)d_in[11];
    const float* bR2 = (const float*)d_in[12];
    const float* bI2 = (const float*)d_in[13];
    const float* bR3 = (const float*)d_in[14];
    const float* bI3 = (const float*)d_in[15];
    const float* bR4 = (const float*)d_in[16];
    const float* bI4 = (const float*)d_in[17];

    float* sums = (float*)d_ws;          // 8 * 512 floats = 16 KB
    float* out  = (float*)d_out;

    // Kernel 1: row sums of the 8 weight matrices (4096 waves)
    {
        int threads = 8 * Ec * 64;       // 262144
        int block = 256;
        int grid = (threads + block - 1) / block;   // 1024
        rowsum_kernel<<<grid, block, 0, stream>>>(y1r, y1i, y2r, y2i,
                                                  y3r, y3i, y4r, y4i, sums);
    }

    // Kernel 2: fused elementwise octonion multiply + shrink + bias
    {
        int n4 = Nc / 4;                 // 1048576 threads
        int block = 256;
        int grid = n4 / block;           // 4096
        octmlp_kernel<<<grid, block, 0, stream>>>(xr, xi, sums,
                                                  bR1, bI1, bR2, bI2,
                                                  bR3, bI3, bR4, bI4, out);
    }
}

// Round 2
// 58.459 us; speedup vs baseline: 1.0200x; 1.0200x over previous
//
#include <hip/hip_runtime.h>

// OctMLP: x (B,S,4,E) complex pairs, weights reduced to row-sum vectors,
// elementwise octonion-ish multiply with soft-shrink, bias, shrink, stack.
// Memory-bound: ~277 MB total traffic -> target ~45 us at 6.3 TB/s mixed R/W.
//
// R1: bias loaded JIT in epilogue (-32 live VGPRs), med3-based shrink
// (2 ops vs 3-4), __launch_bounds__(256,4) to force >=4 waves/SIMD.

constexpr int Bc = 8, Sc = 1024, Ec = 512;
constexpr int Nc = Bc * Sc * Ec;          // 4194304 elements per plane
constexpr float LAM = 0.01f;

__device__ __forceinline__ float sshrink(float v) {
    // v - clamp(v,-L,L) == soft shrink; med3 is the 1-instr clamp (v_med3_f32)
    return v - __builtin_amdgcn_fmed3f(v, -LAM, LAM);
}

// One wave (64 lanes) per row; 8 matrices x 512 rows = 4096 waves.
__global__ __launch_bounds__(256) void rowsum_kernel(
    const float* __restrict__ y1r, const float* __restrict__ y1i,
    const float* __restrict__ y2r, const float* __restrict__ y2i,
    const float* __restrict__ y3r, const float* __restrict__ y3i,
    const float* __restrict__ y4r, const float* __restrict__ y4i,
    float* __restrict__ sums)
{
    int gid  = blockIdx.x * blockDim.x + threadIdx.x;
    int wave = gid >> 6;
    int lane = gid & 63;
    if (wave >= 8 * Ec) return;
    int m   = wave >> 9;   // matrix 0..7
    int row = wave & 511;

    const float* src;
    switch (m) {
        case 0: src = y1r; break;
        case 1: src = y1i; break;
        case 2: src = y2r; break;
        case 3: src = y2i; break;
        case 4: src = y3r; break;
        case 5: src = y3i; break;
        case 6: src = y4r; break;
        default: src = y4i; break;
    }
    const float4* p = reinterpret_cast<const float4*>(src + (size_t)row * Ec);

    float4 a = p[lane], b = p[lane + 64];
    float s = (a.x + a.y) + (a.z + a.w) + (b.x + b.y) + (b.z + b.w);
    #pragma unroll
    for (int off = 32; off >= 1; off >>= 1) s += __shfl_down(s, off, 64);
    if (lane == 0) sums[m * Ec + row] = s;
}

#define F4LD(p) (*reinterpret_cast<const float4*>(p))
#define F4ST(p, v) (*reinterpret_cast<float4*>(p) = (v))
#define ELT(v, j) (reinterpret_cast<const float*>(&(v))[j])
#define ELTW(v, j) (reinterpret_cast<float*>(&(v))[j])

// One thread per 4 consecutive e. N/4 = 1048576 threads.
__global__ __launch_bounds__(256, 4) void octmlp_kernel(
    const float* __restrict__ xr, const float* __restrict__ xi,
    const float* __restrict__ sums,
    const float* __restrict__ bR1, const float* __restrict__ bI1,
    const float* __restrict__ bR2, const float* __restrict__ bI2,
    const float* __restrict__ bR3, const float* __restrict__ bI3,
    const float* __restrict__ bR4, const float* __restrict__ bI4,
    float* __restrict__ out)
{
    constexpr int E4 = Ec / 4;                    // 128 float4 per row
    int idx = blockIdx.x * blockDim.x + threadIdx.x;   // 0 .. N/4-1
    int e4  = idx & (E4 - 1);
    int bs  = idx >> 7;                           // b*S+s
    int e   = e4 * 4;

    const size_t xbase = (size_t)bs * 4 * Ec + e;
    // x[k] components, k = octonion slot 0..3
    float4 x1r = F4LD(xr + xbase + 0 * Ec), x1i = F4LD(xi + xbase + 0 * Ec);
    float4 x2r = F4LD(xr + xbase + 1 * Ec), x2i = F4LD(xi + xbase + 1 * Ec);
    float4 x3r = F4LD(xr + xbase + 2 * Ec), x3i = F4LD(xi + xbase + 2 * Ec);
    float4 x4r = F4LD(xr + xbase + 3 * Ec), x4i = F4LD(xi + xbase + 3 * Ec);

    // sum vectors: layout [m][E], m order = r1,i1,r2,i2,r3,i3,r4,i4 (L1/L2-hot)
    float4 R1 = F4LD(sums + 0 * Ec + e), I1 = F4LD(sums + 1 * Ec + e);
    float4 R2 = F4LD(sums + 2 * Ec + e), I2 = F4LD(sums + 3 * Ec + e);
    float4 R3 = F4LD(sums + 4 * Ec + e), I3 = F4LD(sums + 5 * Ec + e);
    float4 R4 = F4LD(sums + 6 * Ec + e), I4 = F4LD(sums + 7 * Ec + e);

    float4 o1r, o1i, o2r, o2i, o3r, o3i, o4r, o4i;

    #pragma unroll
    for (int j = 0; j < 4; ++j) {
        float a1r = ELT(x1r, j), a1i = ELT(x1i, j);
        float a2r = ELT(x2r, j), a2i = ELT(x2i, j);
        float a3r = ELT(x3r, j), a3i = ELT(x3i, j);
        float a4r = ELT(x4r, j), a4i = ELT(x4i, j);
        float r1 = ELT(R1, j), i1 = ELT(I1, j);
        float r2 = ELT(R2, j), i2 = ELT(I2, j);
        float r3 = ELT(R3, j), i3 = ELT(I3, j);
        float r4 = ELT(R4, j), i4 = ELT(I4, j);

        // cmul normal (s = r + i*I):  re = sh(xr*r - xi*i), im = sh(xr*i + xi*r)
        // cmul conj   (s = r - i*I):  re = sh(xr*r + xi*i), im = sh(xi*r - xr*i)
        #define CMUL(or_, oi_, xr_, xi_, r_, i_) \
            float or_ = sshrink(fmaf((xr_), (r_), -(xi_) * (i_))); \
            float oi_ = sshrink(fmaf((xr_), (i_),  (xi_) * (r_)));
        #define CMULC(or_, oi_, xr_, xi_, r_, i_) \
            float or_ = sshrink(fmaf((xr_), (r_),  (xi_) * (i_))); \
            float oi_ = sshrink(fmaf((xi_), (r_), -(xr_) * (i_)));

        // a1 = cmul(x1,c1) - cmulc(x2,c2) - cmulc(x3,c3) - cmulc(x4,c4)
        CMUL (p11r, p11i, a1r, a1i, r1, i1)
        CMULC(p12r, p12i, a2r, a2i, r2, i2)
        CMULC(p13r, p13i, a3r, a3i, r3, i3)
        CMULC(p14r, p14i, a4r, a4i, r4, i4)
        ELTW(o1r, j) = (p11r - p12r) - (p13r + p14r);
        ELTW(o1i, j) = (p11i - p12i) - (p13i + p14i);

        // a2 = cmul(x2,c1) + cmul(x1,c2) + cmulc(x4,c3) - cmulc(x3,c4)
        CMUL (p21r, p21i, a2r, a2i, r1, i1)
        CMUL (p22r, p22i, a1r, a1i, r2, i2)
        CMULC(p23r, p23i, a4r, a4i, r3, i3)
        CMULC(p24r, p24i, a3r, a3i, r4, i4)
        ELTW(o2r, j) = (p21r + p22r) + (p23r - p24r);
        ELTW(o2i, j) = (p21i + p22i) + (p23i - p24i);

        // a3 = cmul(x3,c1) - cmulc(x4,c2) + cmul(x1,c3) + cmulc(x2,c4)
        CMUL (p31r, p31i, a3r, a3i, r1, i1)
        CMULC(p32r, p32i, a4r, a4i, r2, i2)
        CMUL (p33r, p33i, a1r, a1i, r3, i3)
        CMULC(p34r, p34i, a2r, a2i, r4, i4)
        ELTW(o3r, j) = (p31r - p32r) + (p33r + p34r);
        ELTW(o3i, j) = (p31i - p32i) + (p33i + p34i);

        // a4 = cmul(x4,c1) + cmulc(x3,c2) - cmulc(x2,c3) + cmul(x1,c4)
        CMUL (p41r, p41i, a4r, a4i, r1, i1)
        CMULC(p42r, p42i, a3r, a3i, r2, i2)
        CMULC(p43r, p43i, a2r, a2i, r3, i3)
        CMUL (p44r, p44i, a1r, a1i, r4, i4)
        ELTW(o4r, j) = (p41r + p42r) - (p43r - p44r);
        ELTW(o4i, j) = (p41i + p42i) - (p43i - p44i);
        #undef CMUL
        #undef CMULC
    }

    // Epilogue: bias loaded JIT (cuts live VGPRs), shrink, strided-plane store.
    float* obase = out + (size_t)bs * Ec + e;
    #define EPI(plane, ov, bp)                                     \
    {                                                              \
        float4 vb = F4LD((bp) + e);                                \
        float4 t;                                                  \
        t.x = sshrink(ELT(ov, 0) + vb.x);                          \
        t.y = sshrink(ELT(ov, 1) + vb.y);                          \
        t.z = sshrink(ELT(ov, 2) + vb.z);                          \
        t.w = sshrink(ELT(ov, 3) + vb.w);                          \
        F4ST(obase + (size_t)(plane) * Nc, t);                     \
    }
    EPI(0, o1r, bR1)
    EPI(1, o1i, bI1)
    EPI(2, o2r, bR2)
    EPI(3, o2i, bI2)
    EPI(4, o3r, bR3)
    EPI(5, o3i, bI3)
    EPI(6, o4r, bR4)
    EPI(7, o4i, bI4)
    #undef EPI
}

extern "C" void kernel_launch(void* const* d_in, const int* in_sizes, int n_in,
                              void* d_out, int out_size, void* d_ws, size_t ws_size,
                              hipStream_t stream) {
    const float* xr  = (const float*)d_in[0];
    const float* xi  = (const float*)d_in[1];
    const float* y1r = (const float*)d_in[2];
    const float* y1i = (const float*)d_in[3];
    const float* y2r = (const float*)d_in[4];
    const float* y2i = (const float*)d_in[5];
    const float* y3r = (const float*)d_in[6];
    const float* y3i = (const float*)d_in[7];
    const float* y4r = (const float*)d_in[8];
    const float* y4i = (const float*)d_in[9];
    const float* bR1 = (const float*)d_in[10];
    const float* bI1 = (const float*)d_in[11];
    const float* bR2 = (const float*)d_in[12];
    const float* bI2 = (const float*)d_in[13];
    const float* bR3 = (const float*)d_in[14];
    const float* bI3 = (const float*)d_in[15];
    const float* bR4 = (const float*)d_in[16];
    const float* bI4 = (const float*)d_in[17];

    float* sums = (float*)d_ws;          // 8 * 512 floats = 16 KB
    float* out  = (float*)d_out;

    // Kernel 1: row sums of the 8 weight matrices (4096 waves)
    {
        int threads = 8 * Ec * 64;       // 262144
        int block = 256;
        int grid = (threads + block - 1) / block;   // 1024
        rowsum_kernel<<<grid, block, 0, stream>>>(y1r, y1i, y2r, y2i,
                                                  y3r, y3i, y4r, y4i, sums);
    }

    // Kernel 2: fused elementwise octonion multiply + shrink + bias
    {
        int n4 = Nc / 4;                 // 1048576 threads
        int block = 256;
        int grid = n4 / block;           // 4096
        octmlp_kernel<<<grid, block, 0, stream>>>(xr, xi, sums,
                                                  bR1, bI1, bR2, bI2,
                                                  bR3, bI3, bR4, bI4, out);
    }
}

// Round 4
// 48.701 us; speedup vs baseline: 1.2243x; 1.2003x over previous
//
#include <hip/hip_runtime.h>

// OctMLP: x (B,S,4,E) complex pairs, weights reduced to row-sum vectors,
// elementwise octonion-ish multiply with soft-shrink, bias, shrink, stack.
//
// R3 (= R2 with compile fix): NON-TEMPORAL stores for the 8 output planes.
// Output (128MB/replay) is written once, never re-read on-device; regular
// stores write-allocate in L2/L3 and evict x (R1 counters: FETCH=64MB = only
// half of x stayed L3-resident). nt stores stream the writes, letting
// x(128MB)+weights(8MB) stay fully L3-resident -> HBM fetch ~0.
// __builtin_nontemporal_store needs a NATIVE vector type, not HIP float4.

constexpr int Bc = 8, Sc = 1024, Ec = 512;
constexpr int Nc = Bc * Sc * Ec;          // 4194304 elements per plane
constexpr float LAM = 0.01f;

typedef float floatx4 __attribute__((ext_vector_type(4)));

__device__ __forceinline__ float sshrink(float v) {
    // v - clamp(v,-L,L) == soft shrink; med3 is the 1-instr clamp (v_med3_f32)
    return v - __builtin_amdgcn_fmed3f(v, -LAM, LAM);
}

// One wave (64 lanes) per row; 8 matrices x 512 rows = 4096 waves.
__global__ __launch_bounds__(256) void rowsum_kernel(
    const float* __restrict__ y1r, const float* __restrict__ y1i,
    const float* __restrict__ y2r, const float* __restrict__ y2i,
    const float* __restrict__ y3r, const float* __restrict__ y3i,
    const float* __restrict__ y4r, const float* __restrict__ y4i,
    float* __restrict__ sums)
{
    int gid  = blockIdx.x * blockDim.x + threadIdx.x;
    int wave = gid >> 6;
    int lane = gid & 63;
    if (wave >= 8 * Ec) return;
    int m   = wave >> 9;   // matrix 0..7
    int row = wave & 511;

    const float* src;
    switch (m) {
        case 0: src = y1r; break;
        case 1: src = y1i; break;
        case 2: src = y2r; break;
        case 3: src = y2i; break;
        case 4: src = y3r; break;
        case 5: src = y3i; break;
        case 6: src = y4r; break;
        default: src = y4i; break;
    }
    const float4* p = reinterpret_cast<const float4*>(src + (size_t)row * Ec);

    float4 a = p[lane], b = p[lane + 64];
    float s = (a.x + a.y) + (a.z + a.w) + (b.x + b.y) + (b.z + b.w);
    #pragma unroll
    for (int off = 32; off >= 1; off >>= 1) s += __shfl_down(s, off, 64);
    if (lane == 0) sums[m * Ec + row] = s;
}

#define F4LD(p) (*reinterpret_cast<const float4*>(p))
#define ELT(v, j) (reinterpret_cast<const float*>(&(v))[j])
#define ELTW(v, j) (reinterpret_cast<float*>(&(v))[j])

__device__ __forceinline__ void nt_store4(float* p, float a, float b, float c, float d) {
    floatx4 v = { a, b, c, d };
    __builtin_nontemporal_store(v, reinterpret_cast<floatx4*>(p));
}

// One thread per 4 consecutive e. N/4 = 1048576 threads.
__global__ __launch_bounds__(256, 4) void octmlp_kernel(
    const float* __restrict__ xr, const float* __restrict__ xi,
    const float* __restrict__ sums,
    const float* __restrict__ bR1, const float* __restrict__ bI1,
    const float* __restrict__ bR2, const float* __restrict__ bI2,
    const float* __restrict__ bR3, const float* __restrict__ bI3,
    const float* __restrict__ bR4, const float* __restrict__ bI4,
    float* __restrict__ out)
{
    constexpr int E4 = Ec / 4;                    // 128 float4 per row
    int idx = blockIdx.x * blockDim.x + threadIdx.x;   // 0 .. N/4-1
    int e4  = idx & (E4 - 1);
    int bs  = idx >> 7;                           // b*S+s
    int e   = e4 * 4;

    const size_t xbase = (size_t)bs * 4 * Ec + e;
    // x[k] components, k = octonion slot 0..3
    float4 x1r = F4LD(xr + xbase + 0 * Ec), x1i = F4LD(xi + xbase + 0 * Ec);
    float4 x2r = F4LD(xr + xbase + 1 * Ec), x2i = F4LD(xi + xbase + 1 * Ec);
    float4 x3r = F4LD(xr + xbase + 2 * Ec), x3i = F4LD(xi + xbase + 2 * Ec);
    float4 x4r = F4LD(xr + xbase + 3 * Ec), x4i = F4LD(xi + xbase + 3 * Ec);

    // sum vectors: layout [m][E], m order = r1,i1,r2,i2,r3,i3,r4,i4 (L1/L2-hot)
    float4 R1 = F4LD(sums + 0 * Ec + e), I1 = F4LD(sums + 1 * Ec + e);
    float4 R2 = F4LD(sums + 2 * Ec + e), I2 = F4LD(sums + 3 * Ec + e);
    float4 R3 = F4LD(sums + 4 * Ec + e), I3 = F4LD(sums + 5 * Ec + e);
    float4 R4 = F4LD(sums + 6 * Ec + e), I4 = F4LD(sums + 7 * Ec + e);

    float4 o1r, o1i, o2r, o2i, o3r, o3i, o4r, o4i;

    #pragma unroll
    for (int j = 0; j < 4; ++j) {
        float a1r = ELT(x1r, j), a1i = ELT(x1i, j);
        float a2r = ELT(x2r, j), a2i = ELT(x2i, j);
        float a3r = ELT(x3r, j), a3i = ELT(x3i, j);
        float a4r = ELT(x4r, j), a4i = ELT(x4i, j);
        float r1 = ELT(R1, j), i1 = ELT(I1, j);
        float r2 = ELT(R2, j), i2 = ELT(I2, j);
        float r3 = ELT(R3, j), i3 = ELT(I3, j);
        float r4 = ELT(R4, j), i4 = ELT(I4, j);

        // cmul normal (s = r + i*I):  re = sh(xr*r - xi*i), im = sh(xr*i + xi*r)
        // cmul conj   (s = r - i*I):  re = sh(xr*r + xi*i), im = sh(xi*r - xr*i)
        #define CMUL(or_, oi_, xr_, xi_, r_, i_) \
            float or_ = sshrink(fmaf((xr_), (r_), -(xi_) * (i_))); \
            float oi_ = sshrink(fmaf((xr_), (i_),  (xi_) * (r_)));
        #define CMULC(or_, oi_, xr_, xi_, r_, i_) \
            float or_ = sshrink(fmaf((xr_), (r_),  (xi_) * (i_))); \
            float oi_ = sshrink(fmaf((xi_), (r_), -(xr_) * (i_)));

        // a1 = cmul(x1,c1) - cmulc(x2,c2) - cmulc(x3,c3) - cmulc(x4,c4)
        CMUL (p11r, p11i, a1r, a1i, r1, i1)
        CMULC(p12r, p12i, a2r, a2i, r2, i2)
        CMULC(p13r, p13i, a3r, a3i, r3, i3)
        CMULC(p14r, p14i, a4r, a4i, r4, i4)
        ELTW(o1r, j) = (p11r - p12r) - (p13r + p14r);
        ELTW(o1i, j) = (p11i - p12i) - (p13i + p14i);

        // a2 = cmul(x2,c1) + cmul(x1,c2) + cmulc(x4,c3) - cmulc(x3,c4)
        CMUL (p21r, p21i, a2r, a2i, r1, i1)
        CMUL (p22r, p22i, a1r, a1i, r2, i2)
        CMULC(p23r, p23i, a4r, a4i, r3, i3)
        CMULC(p24r, p24i, a3r, a3i, r4, i4)
        ELTW(o2r, j) = (p21r + p22r) + (p23r - p24r);
        ELTW(o2i, j) = (p21i + p22i) + (p23i - p24i);

        // a3 = cmul(x3,c1) - cmulc(x4,c2) + cmul(x1,c3) + cmulc(x2,c4)
        CMUL (p31r, p31i, a3r, a3i, r1, i1)
        CMULC(p32r, p32i, a4r, a4i, r2, i2)
        CMUL (p33r, p33i, a1r, a1i, r3, i3)
        CMULC(p34r, p34i, a2r, a2i, r4, i4)
        ELTW(o3r, j) = (p31r - p32r) + (p33r + p34r);
        ELTW(o3i, j) = (p31i - p32i) + (p33i + p34i);

        // a4 = cmul(x4,c1) + cmulc(x3,c2) - cmulc(x2,c3) + cmul(x1,c4)
        CMUL (p41r, p41i, a4r, a4i, r1, i1)
        CMULC(p42r, p42i, a3r, a3i, r2, i2)
        CMULC(p43r, p43i, a2r, a2i, r3, i3)
        CMUL (p44r, p44i, a1r, a1i, r4, i4)
        ELTW(o4r, j) = (p41r + p42r) - (p43r - p44r);
        ELTW(o4i, j) = (p41i + p42i) - (p43i - p44i);
        #undef CMUL
        #undef CMULC
    }

    // Epilogue: bias loaded JIT, shrink, NON-TEMPORAL strided-plane store.
    float* obase = out + (size_t)bs * Ec + e;
    #define EPI(plane, ov, bp)                                     \
    {                                                              \
        float4 vb = F4LD((bp) + e);                                \
        nt_store4(obase + (size_t)(plane) * Nc,                    \
                  sshrink(ELT(ov, 0) + vb.x),                      \
                  sshrink(ELT(ov, 1) + vb.y),                      \
                  sshrink(ELT(ov, 2) + vb.z),                      \
                  sshrink(ELT(ov, 3) + vb.w));                     \
    }
    EPI(0, o1r, bR1)
    EPI(1, o1i, bI1)
    EPI(2, o2r, bR2)
    EPI(3, o2i, bI2)
    EPI(4, o3r, bR3)
    EPI(5, o3i, bI3)
    EPI(6, o4r, bR4)
    EPI(7, o4i, bI4)
    #undef EPI
}

extern "C" void kernel_launch(void* const* d_in, const int* in_sizes, int n_in,
                              void* d_out, int out_size, void* d_ws, size_t ws_size,
                              hipStream_t stream) {
    const float* xr  = (const float*)d_in[0];
    const float* xi  = (const float*)d_in[1];
    const float* y1r = (const float*)d_in[2];
    const float* y1i = (const float*)d_in[3];
    const float* y2r = (const float*)d_in[4];
    const float* y2i = (const float*)d_in[5];
    const float* y3r = (const float*)d_in[6];
    const float* y3i = (const float*)d_in[7];
    const float* y4r = (const float*)d_in[8];
    const float* y4i = (const float*)d_in[9];
    const float* bR1 = (const float*)d_in[10];
    const float* bI1 = (const float*)d_in[11];
    const float* bR2 = (const float*)d_in[12];
    const float* bI2 = (const float*)d_in[13];
    const float* bR3 = (const float*)d_in[14];
    const float* bI3 = (const float*)d_in[15];
    const float* bR4 = (const float*)d_in[16];
    const float* bI4 = (const float*)d_in[17];

    float* sums = (float*)d_ws;          // 8 * 512 floats = 16 KB
    float* out  = (float*)d_out;

    // Kernel 1: row sums of the 8 weight matrices (4096 waves)
    {
        int threads = 8 * Ec * 64;       // 262144
        int block = 256;
        int grid = (threads + block - 1) / block;   // 1024
        rowsum_kernel<<<grid, block, 0, stream>>>(y1r, y1i, y2r, y2i,
                                                  y3r, y3i, y4r, y4i, sums);
    }

    // Kernel 2: fused elementwise octonion multiply + shrink + bias
    {
        int n4 = Nc / 4;                 // 1048576 threads
        int block = 256;
        int grid = n4 / block;           // 4096
        octmlp_kernel<<<grid, block, 0, stream>>>(xr, xi, sums,
                                                  bR1, bI1, bR2, bI2,
                                                  bR3, bI3, bR4, bI4, out);
    }
}